// Round 9
// baseline (571.004 us; speedup 1.0000x reference)
//
#include <hip/hip_runtime.h>
#include <math.h>

// ---------------------------------------------------------------------------
// TransformerBlock: B=2 S=2048 DIM=1024 H=16 hd=64 FFN=4096, fp32 in/out.
// R8: revert R7's regressions (GEMM rotation, attn mask dbuf) to R6/R4
// known-good. New: (a) W2 split-K=4 via fp32 agent-scope atomics onto out
// pre-initialized to x2 by ln2 (W2 was 2 blocks/CU at K=4096 — worst GEMM);
// (b) ln1 + all 6 weight transposes fused into one 1D-grid prep kernel
// (12 -> 9 launches).
// ---------------------------------------------------------------------------

#define DIMSZ 1024
#define SEQ   2048
#define BATCH 2
#define NHEAD 16
#define HD    64
#define FFNSZ 4096
#define ROWS  (BATCH*SEQ)   // 4096
#define KSPLIT 2
#define KRANGE (SEQ/KSPLIT) // 1024 keys per partial

typedef __attribute__((ext_vector_type(8))) short bf8_t;   // 8 x bf16 (4 VGPR)
typedef __attribute__((ext_vector_type(4))) float f4_t;    // 4 x f32

// round-to-nearest-even float -> bf16 (bit pattern)
__device__ __forceinline__ unsigned short f2bf(float f) {
  union { float f; unsigned u; } c; c.f = f;
  unsigned u = c.u;
  return (unsigned short)((u + 0x7fffu + ((u >> 16) & 1u)) >> 16);
}

__device__ __forceinline__ float bf2f(unsigned short u) {
  union { unsigned u; float f; } c; c.u = ((unsigned)u) << 16; return c.f;
}

__device__ __forceinline__ float fast_exp2(float x) {
#if __has_builtin(__builtin_amdgcn_exp2f)
  return __builtin_amdgcn_exp2f(x);   // v_exp_f32 is natively 2^x
#else
  return exp2f(x);
#endif
}

__device__ __forceinline__ float fast_rcp(float x) {
#if __has_builtin(__builtin_amdgcn_rcpf)
  return __builtin_amdgcn_rcpf(x);
#else
  return 1.f / x;
#endif
}

// exact-GELU via A&S 7.1.26 erf approx (|err| ~1.5e-7 in erf)
__device__ __forceinline__ float gelu_fast(float x) {
  float ax = fabsf(x) * 0.70710678118654752f;
  float t  = fast_rcp(fmaf(0.3275911f, ax, 1.f));
  float p  = fmaf(t, 1.061405429f, -1.453152027f);
  p = fmaf(t, p, 1.421413741f);
  p = fmaf(t, p, -0.284496736f);
  p = fmaf(t, p, 0.254829592f);
  p = p * t;
  float e  = fast_exp2(-ax * ax * 1.4426950408889634f);
  float er = fmaf(-p, e, 1.f);
  er = copysignf(er, x);
  return 0.5f * x * (1.f + er);
}

// pack hi16(a),hi16(b) -> (bf16(b)<<16)|bf16(a)  [truncating cvt, 1 instr]
__device__ __forceinline__ unsigned int pk_trunc_bf16(float a, float b) {
#if __has_builtin(__builtin_amdgcn_perm)
  return __builtin_amdgcn_perm(__float_as_uint(b), __float_as_uint(a), 0x07060302u);
#else
  return (__float_as_uint(b) & 0xffff0000u) | (__float_as_uint(a) >> 16);
#endif
}

__device__ __forceinline__ void async16(const void* g, void* l) {
  __builtin_amdgcn_global_load_lds((const __attribute__((address_space(1))) void*)g,
                                   (__attribute__((address_space(3))) void*)l,
                                   16, 0, 0);
}

__device__ __forceinline__ f4_t mfma_bf16(bf8_t a, bf8_t b, f4_t c) {
  return __builtin_amdgcn_mfma_f32_16x16x32_bf16(a, b, c, 0, 0, 0);
}

// native fp32 atomic add, agent scope (global_atomic_add_f32 on gfx950)
__device__ __forceinline__ void atom_add_f32(float* p, float v) {
  __hip_atomic_fetch_add(p, v, __ATOMIC_RELAXED, __HIP_MEMORY_SCOPE_AGENT);
}

// ---------------------------------------------------------------------------
// PREP kernel: one launch does ln1 + all weight cast+transposes.
// 1D grid, 13312 blocks of 256:
//   [0,4096)      : wq/wk/wv/wo 1024x1024 transpose (1024 32x32-tiles each)
//   [4096,8192)   : w1 (K=1024,N=4096) -> w1T[4096][1024]
//   [8192,12288)  : w2 (K=4096,N=1024) -> w2T[1024][4096]
//   [12288,13312) : ln1 rows (4 rows per block)
// ---------------------------------------------------------------------------
__global__ __launch_bounds__(256) void prep_kernel(
    const float* __restrict__ x,  const float* __restrict__ ln1w,
    const float* __restrict__ ln1b, unsigned short* __restrict__ h1,
    const float* __restrict__ wq, const float* __restrict__ wk,
    const float* __restrict__ wv, const float* __restrict__ wo,
    const float* __restrict__ w1, const float* __restrict__ w2,
    unsigned short* __restrict__ wqkvT, unsigned short* __restrict__ woT,
    unsigned short* __restrict__ w1T,   unsigned short* __restrict__ w2T) {
  __shared__ float t[32][33];
  int id = blockIdx.x;
  if (id >= 12288) {
    // ----- ln1 -----
    int row  = (id - 12288) * 4 + (threadIdx.x >> 6);
    int lane = threadIdx.x & 63;
    const float4* xr = (const float4*)(x + (size_t)row * DIMSZ);
    float4 v[4];
    float s = 0.f, s2 = 0.f;
#pragma unroll
    for (int i = 0; i < 4; ++i) {
      v[i] = xr[lane + 64*i];
      s  += (v[i].x + v[i].y) + (v[i].z + v[i].w);
      s2 += (v[i].x*v[i].x + v[i].y*v[i].y) + (v[i].z*v[i].z + v[i].w*v[i].w);
    }
#pragma unroll
    for (int off = 32; off; off >>= 1) {
      s  += __shfl_xor(s,  off);
      s2 += __shfl_xor(s2, off);
    }
    float mean = s * (1.f/DIMSZ);
    float var  = s2 * (1.f/DIMSZ) - mean*mean;
    float rstd = rsqrtf(var + 1e-12f);
#pragma unroll
    for (int i = 0; i < 4; ++i) {
      float4 wv4 = ((const float4*)ln1w)[lane + 64*i];
      float4 bv4 = ((const float4*)ln1b)[lane + 64*i];
      ushort4 o;
      o.x = f2bf((v[i].x - mean) * rstd * wv4.x + bv4.x);
      o.y = f2bf((v[i].y - mean) * rstd * wv4.y + bv4.y);
      o.z = f2bf((v[i].z - mean) * rstd * wv4.z + bv4.z);
      o.w = f2bf((v[i].w - mean) * rstd * wv4.w + bv4.w);
      *(ushort4*)(h1 + (size_t)row * DIMSZ + (size_t)(lane + 64*i) * 4) = o;
    }
    return;
  }
  // ----- weight transpose tile -----
  const float* w; unsigned short* wT; int K, N, n0, k0;
  if (id < 4096) {
    int wsel = id >> 10, tt = id & 1023;
    K = 1024; N = 1024;
    n0 = (tt & 31) * 32; k0 = (tt >> 5) * 32;
    w  = (wsel == 0) ? wq : (wsel == 1) ? wk : (wsel == 2) ? wv : wo;
    wT = (wsel == 0) ? wqkvT : (wsel == 1) ? wqkvT + 1024*1024
       : (wsel == 2) ? wqkvT + 2*1024*1024 : woT;
  } else if (id < 8192) {
    int tt = id - 4096;
    K = 1024; N = 4096;
    n0 = (tt & 127) * 32; k0 = (tt >> 7) * 32;
    w = w1; wT = w1T;
  } else {
    int tt = id - 8192;
    K = 4096; N = 1024;
    n0 = (tt & 31) * 32; k0 = (tt >> 5) * 32;
    w = w2; wT = w2T;
  }
  int tx = threadIdx.x & 31, ty = threadIdx.x >> 5;
#pragma unroll
  for (int i = 0; i < 4; ++i)
    t[ty + 8*i][tx] = w[(size_t)(k0 + ty + 8*i) * N + n0 + tx];
  __syncthreads();
#pragma unroll
  for (int i = 0; i < 4; ++i)
    wT[(size_t)(n0 + ty + 8*i) * K + k0 + tx] = f2bf(t[tx][ty + 8*i]);
}

// ---------------------------------------------------------------------------
// LayerNorm (standalone, used for ln2): optionally also copies x -> cpy
// (fp32), pre-initializing `out` for the atomic split-K W2 GEMM.
// ---------------------------------------------------------------------------
__global__ __launch_bounds__(256) void ln_kernel(const float* __restrict__ x,
                                                 const float* __restrict__ w,
                                                 const float* __restrict__ b,
                                                 unsigned short* __restrict__ out,
                                                 float* __restrict__ cpy) {
  int row  = blockIdx.x * 4 + (threadIdx.x >> 6);
  int lane = threadIdx.x & 63;
  const float4* xr = (const float4*)(x + (size_t)row * DIMSZ);
  float4 v[4];
  float s = 0.f, s2 = 0.f;
#pragma unroll
  for (int i = 0; i < 4; ++i) {
    v[i] = xr[lane + 64*i];
    s  += (v[i].x + v[i].y) + (v[i].z + v[i].w);
    s2 += (v[i].x*v[i].x + v[i].y*v[i].y) + (v[i].z*v[i].z + v[i].w*v[i].w);
  }
#pragma unroll
  for (int off = 32; off; off >>= 1) {
    s  += __shfl_xor(s,  off);
    s2 += __shfl_xor(s2, off);
  }
  float mean = s * (1.f/DIMSZ);
  float var  = s2 * (1.f/DIMSZ) - mean*mean;
  float rstd = rsqrtf(var + 1e-12f);
#pragma unroll
  for (int i = 0; i < 4; ++i) {
    float4 wv = ((const float4*)w)[lane + 64*i];
    float4 bv = ((const float4*)b)[lane + 64*i];
    ushort4 o;
    o.x = f2bf((v[i].x - mean) * rstd * wv.x + bv.x);
    o.y = f2bf((v[i].y - mean) * rstd * wv.y + bv.y);
    o.z = f2bf((v[i].z - mean) * rstd * wv.z + bv.z);
    o.w = f2bf((v[i].w - mean) * rstd * wv.w + bv.w);
    *(ushort4*)(out + (size_t)row * DIMSZ + (size_t)(lane + 64*i) * 4) = o;
    if (cpy) ((float4*)(cpy + (size_t)row * DIMSZ))[lane + 64*i] = v[i];
  }
}

// ---------------------------------------------------------------------------
// V transpose: qkv[(b*S+s)*3072 + 2048 + h*64 + d] -> vt[(bh*64+d)*S + s]
// ---------------------------------------------------------------------------
__global__ __launch_bounds__(256) void vt_kernel(const unsigned short* __restrict__ qkv,
                                                 unsigned short* __restrict__ vt) {
  __shared__ unsigned short tile[64][65];
  int bh = blockIdx.y, b = bh >> 4, h = bh & 15;
  int s0 = blockIdx.x * 64;
  int tx = threadIdx.x & 63, ty = threadIdx.x >> 6;
#pragma unroll
  for (int i = 0; i < 16; ++i) {
    int s = ty + i*4;
    tile[s][tx] = qkv[((size_t)(b*SEQ) + s0 + s) * 3072 + 2048 + h*HD + tx];
  }
  __syncthreads();
#pragma unroll
  for (int i = 0; i < 16; ++i) {
    int d = ty + i*4;
    vt[((size_t)bh * HD + d) * SEQ + s0 + tx] = tile[tx][d];
  }
}

// ---------------------------------------------------------------------------
// GEMM (R4 structure — known good): C[M,N] = epi( A[M,K] @ Bt[N,K]^T ).
// Swapped MFMA operands (D = C^T tile -> vectorized epilogue). BK=64 staged
// as two 32-halves in one barrier-pair (32 MFMA between barriers).
// NT = 128 or 64. grid = (N/NT, M/128, Z); klen = K-range per z-slice.
// EPI: 0 = bf16; 1 = bf16 gelu; 2 = f32 += res; 3 = f32 atomic add.
// ---------------------------------------------------------------------------
template<int EPI, int NT>
__global__ __launch_bounds__(256) void gemm_bt(const unsigned short* __restrict__ A,
                                               const unsigned short* __restrict__ Bt,
                                               void* __restrict__ Cv,
                                               const float* __restrict__ res,
                                               int M, int N, int K, int klen) {
  constexpr int JT = NT / 32;              // j-tiles per wave (4 or 2)
  __shared__ unsigned short As[2][128][32];
  __shared__ unsigned short Bs[2][NT][32];
  int tid  = threadIdx.x;
  int wv   = tid >> 6, lane = tid & 63, quad = lane >> 4, ml = lane & 15;
  int wrow = (wv >> 1) * 64, wcol = (wv & 1) * (NT/2);
  const unsigned short* Ab = A  + (size_t)blockIdx.y * 128 * K;
  const unsigned short* Bb = Bt + (size_t)blockIdx.x * NT  * K;
  int kbeg = blockIdx.z * klen;

  f4_t acc[4][JT];
#pragma unroll
  for (int i = 0; i < 4; ++i)
#pragma unroll
    for (int j = 0; j < JT; ++j) acc[i][j] = (f4_t){0.f, 0.f, 0.f, 0.f};

  int r0 = tid >> 2, c0 = (tid & 3) * 8;   // 64 rows x 4 chunks of 8 bf16

  for (int k0 = kbeg; k0 < kbeg + klen; k0 += 64) {
#pragma unroll
    for (int h = 0; h < 2; ++h) {
      const unsigned short* ap = Ab + (size_t)r0 * K + k0 + h*32 + c0;
      async16(ap,          &As[h][r0][c0]);
      async16(ap + 64*K,   &As[h][r0 + 64][c0]);
      const unsigned short* bp = Bb + (size_t)r0 * K + k0 + h*32 + c0;
      async16(bp,          &Bs[h][r0][c0]);
      if constexpr (NT == 128)
        async16(bp + 64*K, &Bs[h][r0 + 64][c0]);
    }
    __syncthreads();

#pragma unroll
    for (int h = 0; h < 2; ++h) {
      bf8_t af[4], bfr[JT];
#pragma unroll
      for (int i = 0; i < 4; ++i)
        af[i] = *(const bf8_t*)(&As[h][wrow + i*16 + ml][quad * 8]);
#pragma unroll
      for (int j = 0; j < JT; ++j)
        bfr[j] = *(const bf8_t*)(&Bs[h][wcol + j*16 + ml][quad * 8]);
#pragma unroll
      for (int i = 0; i < 4; ++i)
#pragma unroll
        for (int j = 0; j < JT; ++j)
          acc[i][j] = mfma_bf16(bfr[j], af[i], acc[i][j]);   // swapped: D=C^T
    }
    __syncthreads();
  }

  // epilogue: lane holds C[m = wrow+i*16+ml][n = wcol+j*16+quad*4 .. +3]
#pragma unroll
  for (int i = 0; i < 4; ++i) {
    int m = blockIdx.y * 128 + wrow + i*16 + ml;
#pragma unroll
    for (int j = 0; j < JT; ++j) {
      int n = blockIdx.x * NT + wcol + j*16 + quad*4;
      size_t off = (size_t)m * N + n;
      if constexpr (EPI == 2) {
        float4 rv = *(const float4*)(res + off);
        float4 ov;
        ov.x = rv.x + acc[i][j][0];
        ov.y = rv.y + acc[i][j][1];
        ov.z = rv.z + acc[i][j][2];
        ov.w = rv.w + acc[i][j][3];
        *(float4*)((float*)Cv + off) = ov;
      } else if constexpr (EPI == 3) {
        float* Co = (float*)Cv + off;
        atom_add_f32(Co + 0, acc[i][j][0]);
        atom_add_f32(Co + 1, acc[i][j][1]);
        atom_add_f32(Co + 2, acc[i][j][2]);
        atom_add_f32(Co + 3, acc[i][j][3]);
      } else {
        float v0 = acc[i][j][0], v1 = acc[i][j][1], v2 = acc[i][j][2], v3 = acc[i][j][3];
        if constexpr (EPI == 1) {
          v0 = gelu_fast(v0); v1 = gelu_fast(v1);
          v2 = gelu_fast(v2); v3 = gelu_fast(v3);
        }
        ushort4 o;
        o.x = f2bf(v0); o.y = f2bf(v1); o.z = f2bf(v2); o.w = f2bf(v3);
        *(ushort4*)((unsigned short*)Cv + off) = o;
      }
    }
  }
}

// ---------------------------------------------------------------------------
// Flash attention partial (R6 structure — known good): 128 q-rows/block,
// 2 Q-frags per wave, split-K (KSPLIT=2). Fixed-base exp2 softmax.
// grid = (SEQ/128, KSPLIT, B*H), block 256.
// ---------------------------------------------------------------------------
__global__ __launch_bounds__(256) void attn_part(const unsigned short* __restrict__ qkv,
                                                 const unsigned short* __restrict__ vt,
                                                 const float* __restrict__ mask,
                                                 unsigned short* __restrict__ pbuf,
                                                 float* __restrict__ lbuf) {
  __shared__ unsigned short Ks[2][64][32];      // [d-half][key][d32]   8 KB
  __shared__ unsigned short Vs[2][64][32];      // [key-half][d][k32]   8 KB
  __shared__ unsigned short Ps[4][2][16][72];   // [wave][qfrag][q][key] 18 KB

  int kz = blockIdx.y;
  int bh = blockIdx.z, b = bh >> 4, h = bh & 15;
  int tid = threadIdx.x;
  int wv = tid >> 6, lane = tid & 63;
  int quad = lane >> 4, ml = lane & 15;
  int q0 = blockIdx.x * 128;
  int qA = q0 + wv * 32 + ml;               // frag 0 q row
  int qB = qA + 16;                         // frag 1 q row
  int kbeg = kz * KRANGE;

  const unsigned short* qrowA = qkv + ((size_t)(b*SEQ) + qA) * 3072 + h*HD;
  const unsigned short* qrowB = qkv + ((size_t)(b*SEQ) + qB) * 3072 + h*HD;
  bf8_t qf[2][2];
  qf[0][0] = *(const bf8_t*)(qrowA + quad*8);
  qf[0][1] = *(const bf8_t*)(qrowA + 32 + quad*8);
  qf[1][0] = *(const bf8_t*)(qrowB + quad*8);
  qf[1][1] = *(const bf8_t*)(qrowB + 32 + quad*8);

  const unsigned short* kbase = qkv + ((size_t)(b*SEQ) + kbeg) * 3072 + DIMSZ + h*HD;
  const unsigned short* vbase = vt + (size_t)bh * HD * SEQ + kbeg;
  const float* mrowA = mask + (size_t)qA * SEQ + kbeg;
  const float* mrowB = mask + (size_t)qB * SEQ + kbeg;

  int srow = tid >> 2;            // 0..63
  int scol = (tid & 3) * 8;       // 0,8,16,24 (ushorts)

  f4_t O[2][4];
#pragma unroll
  for (int g = 0; g < 2; ++g)
#pragma unroll
    for (int dt = 0; dt < 4; ++dt) O[g][dt] = (f4_t){0.f, 0.f, 0.f, 0.f};
  float lR[2] = {0.f, 0.f};

  const float C1 = 0.18033688011112042f;   // 0.125 * log2(e)
  const float C2 = 1.4426950408889634f;    // log2(e)

  for (int t0 = 0; t0 < KRANGE; t0 += 64) {
    float4 mvA[4], mvB[4];
#pragma unroll
    for (int mt = 0; mt < 4; ++mt) {
      mvA[mt] = *(const float4*)(mrowA + t0 + mt*16 + quad*4);
      mvB[mt] = *(const float4*)(mrowB + t0 + mt*16 + quad*4);
    }

    __syncthreads();   // previous chunk's K/V reads done before overwrite
#pragma unroll
    for (int dh = 0; dh < 2; ++dh)
      async16(kbase + (size_t)(t0 + srow) * 3072 + dh*32 + scol,
              &Ks[dh][0][0] + (size_t)tid * 8);
#pragma unroll
    for (int kc = 0; kc < 2; ++kc)
      async16(vbase + (size_t)srow * SEQ + t0 + kc*32 + scol,
              &Vs[kc][0][0] + (size_t)tid * 8);
    __syncthreads();   // staging visible

    // --- S^T = K·Q^T over 64 keys, both q-frags share the K reads ---
#pragma unroll
    for (int mt = 0; mt < 4; ++mt) {
      bf8_t kf0 = *(const bf8_t*)(&Ks[0][mt*16 + ml][quad*8]);
      bf8_t kf1 = *(const bf8_t*)(&Ks[1][mt*16 + ml][quad*8]);
#pragma unroll
      for (int g = 0; g < 2; ++g) {
        f4_t s = (f4_t){0.f, 0.f, 0.f, 0.f};
        s = mfma_bf16(kf0, qf[g][0], s);
        s = mfma_bf16(kf1, qf[g][1], s);
        const float4& mv = g ? mvB[mt] : mvA[mt];
        float p0 = fast_exp2(fmaf(s[0], C1, mv.x * C2));
        float p1 = fast_exp2(fmaf(s[1], C1, mv.y * C2));
        float p2 = fast_exp2(fmaf(s[2], C1, mv.z * C2));
        float p3 = fast_exp2(fmaf(s[3], C1, mv.w * C2));
        lR[g] += (p0 + p1) + (p2 + p3);
        uint2 pk;
        pk.x = pk_trunc_bf16(p0, p1);
        pk.y = pk_trunc_bf16(p2, p3);
        *(uint2*)(&Ps[wv][g][ml][mt*16 + quad*4]) = pk;
      }
    }

    // --- O^T += V^T·P^T, both q-frags share the V reads ---
#pragma unroll
    for (int kc = 0; kc < 2; ++kc) {
      bf8_t pfA = *(const bf8_t*)(&Ps[wv][0][ml][kc*32 + quad*8]);
      bf8_t pfB = *(const bf8_t*)(&Ps[wv][1][ml][kc*32 + quad*8]);
#pragma unroll
      for (int dt = 0; dt < 4; ++dt) {
        bf8_t vf = *(const bf8_t*)(&Vs[kc][dt*16 + ml][quad*8]);
        O[0][dt] = mfma_bf16(vf, pfA, O[0][dt]);
        O[1][dt] = mfma_bf16(vf, pfB, O[1][dt]);
      }
    }
  }

  // reduce l over quads; write partials (no divide)
#pragma unroll
  for (int g = 0; g < 2; ++g) {
    lR[g] += __shfl_xor(lR[g], 16);
    lR[g] += __shfl_xor(lR[g], 32);
    int q = g ? qB : qA;
    size_t pb = ((size_t)(bh * KSPLIT + kz) * SEQ + q) * HD;
#pragma unroll
    for (int dt = 0; dt < 4; ++dt) {
      ushort4 o;
      o.x = f2bf(O[g][dt][0]);
      o.y = f2bf(O[g][dt][1]);
      o.z = f2bf(O[g][dt][2]);
      o.w = f2bf(O[g][dt][3]);
      *(ushort4*)(pbuf + pb + dt*16 + quad*4) = o;
    }
    if (quad == 0)
      lbuf[(size_t)(bh * KSPLIT + kz) * SEQ + q] = lR[g];
  }
}

// ---------------------------------------------------------------------------
// Combine: O = (O0 + O1) / (l0 + l1), bf16 out in [b,s,h*64+d] layout.
// ---------------------------------------------------------------------------
__global__ __launch_bounds__(256) void attn_combine(const unsigned short* __restrict__ pbuf,
                                                    const float* __restrict__ lbuf,
                                                    unsigned short* __restrict__ attno) {
  int t = blockIdx.x * 256 + threadIdx.x;   // [0, BH*SEQ*16)
  int dchunk = t & 15;
  int q = (t >> 4) & (SEQ - 1);
  int bh = t >> 15;                         // SEQ*16 = 32768 = 2^15
  int b = bh >> 4, h = bh & 15;
  size_t o0 = ((size_t)(bh * KSPLIT + 0) * SEQ + q) * HD + dchunk * 4;
  size_t o1 = ((size_t)(bh * KSPLIT + 1) * SEQ + q) * HD + dchunk * 4;
  ushort4 a = *(const ushort4*)(pbuf + o0);
  ushort4 c = *(const ushort4*)(pbuf + o1);
  float l = lbuf[(size_t)(bh * KSPLIT + 0) * SEQ + q]
          + lbuf[(size_t)(bh * KSPLIT + 1) * SEQ + q];
  float inv = 1.f / l;
  ushort4 o;
  o.x = f2bf((bf2f(a.x) + bf2f(c.x)) * inv);
  o.y = f2bf((bf2f(a.y) + bf2f(c.y)) * inv);
  o.z = f2bf((bf2f(a.z) + bf2f(c.z)) * inv);
  o.w = f2bf((bf2f(a.w) + bf2f(c.w)) * inv);
  *(ushort4*)(attno + ((size_t)(b*SEQ) + q) * DIMSZ + h*HD + dchunk*4) = o;
}

// ---------------------------------------------------------------------------
extern "C" void kernel_launch(void* const* d_in, const int* in_sizes, int n_in,
                              void* d_out, int out_size, void* d_ws, size_t ws_size,
                              hipStream_t stream) {
  const float* x    = (const float*)d_in[0];
  const float* mask = (const float*)d_in[1];
  const float* wq   = (const float*)d_in[2];
  const float* wk   = (const float*)d_in[3];
  const float* wvp  = (const float*)d_in[4];
  const float* wo   = (const float*)d_in[5];
  const float* w1   = (const float*)d_in[6];
  const float* w2   = (const float*)d_in[7];
  const float* ln1w = (const float*)d_in[8];
  const float* ln1b = (const float*)d_in[9];
  const float* ln2w = (const float*)d_in[10];
  const float* ln2b = (const float*)d_in[11];
  float* out = (float*)d_out;

  char* ws = (char*)d_ws;
  unsigned short* wqkvT  = (unsigned short*)(ws + 0);           //  6 MiB [3072][1024]
  unsigned short* woT    = (unsigned short*)(ws + 6291456);     //  2 MiB [1024][1024]
  unsigned short* w1T    = (unsigned short*)(ws + 8388608);     //  8 MiB [4096][1024]
  unsigned short* w2T    = (unsigned short*)(ws + 16777216);    //  8 MiB [1024][4096]
  unsigned short* attno  = (unsigned short*)(ws + 25165824);    //  8 MiB [4096][1024]
  float*          x2     = (float*)         (ws + 33554432);    // 16 MiB [4096][1024]
  unsigned short* hbuf   = (unsigned short*)(ws + 50331648);    //  8 MiB h1 then h2
  unsigned short* qkvb   = (unsigned short*)(ws + 58720256);    // 24 MiB [4096][3072]
  unsigned short* vtb    = (unsigned short*)(ws + 83886080);    //  8 MiB [32][64][2048]
  unsigned short* gbuf   = (unsigned short*)(ws + 58720256);    // 32 MiB, reuses qkv+vt
  // split-K partials: pbuf in x2's region (consumed by combine before WO gemm
  // writes x2); lbuf at hbuf start (h1 already consumed; ln2 rewrites later).
  unsigned short* pbuf   = (unsigned short*)(ws + 33554432);
  float*          lbuf   = (float*)         (ws + 50331648);

  // 1. prep: ln1 + all weight transposes (one launch)
  prep_kernel<<<13312, 256, 0, stream>>>(x, ln1w, ln1b, hbuf,
      wq, wk, wvp, wo, w1, w2,
      wqkvT, woT, w1T, w2T);
  // 2. QKV projection
  gemm_bt<0,128><<<dim3(3072/128, 4096/128, 1), 256, 0, stream>>>(hbuf, wqkvT, qkvb, nullptr, ROWS, 3072, 1024, 1024);
  // 3. V -> dim-major
  vt_kernel<<<dim3(SEQ/64, BATCH*NHEAD), 256, 0, stream>>>(qkvb, vtb);
  // 4. attention (split-K partials) + combine
  attn_part<<<dim3(SEQ/128, KSPLIT, BATCH*NHEAD), 256, 0, stream>>>(qkvb, vtb, mask, pbuf, lbuf);
  attn_combine<<<(BATCH*NHEAD*SEQ*(HD/4))/256, 256, 0, stream>>>(pbuf, lbuf, attno);
  // 5. x2 = x + attn @ wo
  gemm_bt<2,64><<<dim3(1024/64, 4096/128, 1), 256, 0, stream>>>(attno, woT, x2, x, ROWS, 1024, 1024, 1024);
  // 6. ln2 -> h2, and pre-init out = x2 for the atomic W2
  ln_kernel<<<ROWS/4, 256, 0, stream>>>(x2, ln2w, ln2b, hbuf, out);
  // 7. g = gelu(h2 @ w1)
  gemm_bt<1,128><<<dim3(4096/128, 4096/128, 1), 256, 0, stream>>>(hbuf, w1T, gbuf, nullptr, ROWS, FFNSZ, 1024, 1024);
  // 8. out += g @ w2   (split-K=4, fp32 atomics; out pre-initialized to x2)
  gemm_bt<3,64><<<dim3(1024/64, 4096/128, 4), 256, 0, stream>>>(gbuf, w2T, out, nullptr, ROWS, 1024, 4096, 1024);

  (void)in_sizes; (void)n_in; (void)out_size; (void)ws_size;
}

// Round 10
// 401.742 us; speedup vs baseline: 1.4213x; 1.4213x over previous
//
#include <hip/hip_runtime.h>
#include <math.h>

// ---------------------------------------------------------------------------
// TransformerBlock: B=2 S=2048 DIM=1024 H=16 hd=64 FFN=4096, fp32 in/out.
// R9: W2 atomics reverted (R8 lesson: agent-scope fp32 atomics onto shared
// lines from all 8 XCDs -> 256 MB of HBM RMW, 240 µs). Split-K kept in the
// XCD-safe form: 2 disjoint bf16 partial buffers + combine (out = x2+p0+p1).
// prep fusion (ln1 + 6 weight transposes in one launch) kept from R8.
// attn = R6 known-good; gemms = R4 known-good structure.
// ---------------------------------------------------------------------------

#define DIMSZ 1024
#define SEQ   2048
#define BATCH 2
#define NHEAD 16
#define HD    64
#define FFNSZ 4096
#define ROWS  (BATCH*SEQ)   // 4096
#define KSPLIT 2
#define KRANGE (SEQ/KSPLIT) // 1024 keys per partial

typedef __attribute__((ext_vector_type(8))) short bf8_t;   // 8 x bf16 (4 VGPR)
typedef __attribute__((ext_vector_type(4))) float f4_t;    // 4 x f32

// round-to-nearest-even float -> bf16 (bit pattern)
__device__ __forceinline__ unsigned short f2bf(float f) {
  union { float f; unsigned u; } c; c.f = f;
  unsigned u = c.u;
  return (unsigned short)((u + 0x7fffu + ((u >> 16) & 1u)) >> 16);
}

__device__ __forceinline__ float bf2f(unsigned short u) {
  union { unsigned u; float f; } c; c.u = ((unsigned)u) << 16; return c.f;
}

__device__ __forceinline__ float fast_exp2(float x) {
#if __has_builtin(__builtin_amdgcn_exp2f)
  return __builtin_amdgcn_exp2f(x);   // v_exp_f32 is natively 2^x
#else
  return exp2f(x);
#endif
}

__device__ __forceinline__ float fast_rcp(float x) {
#if __has_builtin(__builtin_amdgcn_rcpf)
  return __builtin_amdgcn_rcpf(x);
#else
  return 1.f / x;
#endif
}

// exact-GELU via A&S 7.1.26 erf approx (|err| ~1.5e-7 in erf)
__device__ __forceinline__ float gelu_fast(float x) {
  float ax = fabsf(x) * 0.70710678118654752f;
  float t  = fast_rcp(fmaf(0.3275911f, ax, 1.f));
  float p  = fmaf(t, 1.061405429f, -1.453152027f);
  p = fmaf(t, p, 1.421413741f);
  p = fmaf(t, p, -0.284496736f);
  p = fmaf(t, p, 0.254829592f);
  p = p * t;
  float e  = fast_exp2(-ax * ax * 1.4426950408889634f);
  float er = fmaf(-p, e, 1.f);
  er = copysignf(er, x);
  return 0.5f * x * (1.f + er);
}

// pack hi16(a),hi16(b) -> (bf16(b)<<16)|bf16(a)  [truncating cvt, 1 instr]
__device__ __forceinline__ unsigned int pk_trunc_bf16(float a, float b) {
#if __has_builtin(__builtin_amdgcn_perm)
  return __builtin_amdgcn_perm(__float_as_uint(b), __float_as_uint(a), 0x07060302u);
#else
  return (__float_as_uint(b) & 0xffff0000u) | (__float_as_uint(a) >> 16);
#endif
}

__device__ __forceinline__ void async16(const void* g, void* l) {
  __builtin_amdgcn_global_load_lds((const __attribute__((address_space(1))) void*)g,
                                   (__attribute__((address_space(3))) void*)l,
                                   16, 0, 0);
}

__device__ __forceinline__ f4_t mfma_bf16(bf8_t a, bf8_t b, f4_t c) {
  return __builtin_amdgcn_mfma_f32_16x16x32_bf16(a, b, c, 0, 0, 0);
}

// ---------------------------------------------------------------------------
// PREP kernel: one launch does ln1 + all weight cast+transposes.
// 1D grid, 13312 blocks of 256:
//   [0,4096)      : wq/wk/wv/wo 1024x1024 transpose (1024 32x32-tiles each)
//   [4096,8192)   : w1 (K=1024,N=4096) -> w1T[4096][1024]
//   [8192,12288)  : w2 (K=4096,N=1024) -> w2T[1024][4096]
//   [12288,13312) : ln1 rows (4 rows per block)
// ---------------------------------------------------------------------------
__global__ __launch_bounds__(256) void prep_kernel(
    const float* __restrict__ x,  const float* __restrict__ ln1w,
    const float* __restrict__ ln1b, unsigned short* __restrict__ h1,
    const float* __restrict__ wq, const float* __restrict__ wk,
    const float* __restrict__ wv, const float* __restrict__ wo,
    const float* __restrict__ w1, const float* __restrict__ w2,
    unsigned short* __restrict__ wqkvT, unsigned short* __restrict__ woT,
    unsigned short* __restrict__ w1T,   unsigned short* __restrict__ w2T) {
  __shared__ float t[32][33];
  int id = blockIdx.x;
  if (id >= 12288) {
    // ----- ln1 -----
    int row  = (id - 12288) * 4 + (threadIdx.x >> 6);
    int lane = threadIdx.x & 63;
    const float4* xr = (const float4*)(x + (size_t)row * DIMSZ);
    float4 v[4];
    float s = 0.f, s2 = 0.f;
#pragma unroll
    for (int i = 0; i < 4; ++i) {
      v[i] = xr[lane + 64*i];
      s  += (v[i].x + v[i].y) + (v[i].z + v[i].w);
      s2 += (v[i].x*v[i].x + v[i].y*v[i].y) + (v[i].z*v[i].z + v[i].w*v[i].w);
    }
#pragma unroll
    for (int off = 32; off; off >>= 1) {
      s  += __shfl_xor(s,  off);
      s2 += __shfl_xor(s2, off);
    }
    float mean = s * (1.f/DIMSZ);
    float var  = s2 * (1.f/DIMSZ) - mean*mean;
    float rstd = rsqrtf(var + 1e-12f);
#pragma unroll
    for (int i = 0; i < 4; ++i) {
      float4 wv4 = ((const float4*)ln1w)[lane + 64*i];
      float4 bv4 = ((const float4*)ln1b)[lane + 64*i];
      ushort4 o;
      o.x = f2bf((v[i].x - mean) * rstd * wv4.x + bv4.x);
      o.y = f2bf((v[i].y - mean) * rstd * wv4.y + bv4.y);
      o.z = f2bf((v[i].z - mean) * rstd * wv4.z + bv4.z);
      o.w = f2bf((v[i].w - mean) * rstd * wv4.w + bv4.w);
      *(ushort4*)(h1 + (size_t)row * DIMSZ + (size_t)(lane + 64*i) * 4) = o;
    }
    return;
  }
  // ----- weight transpose tile -----
  const float* w; unsigned short* wT; int K, N, n0, k0;
  if (id < 4096) {
    int wsel = id >> 10, tt = id & 1023;
    K = 1024; N = 1024;
    n0 = (tt & 31) * 32; k0 = (tt >> 5) * 32;
    w  = (wsel == 0) ? wq : (wsel == 1) ? wk : (wsel == 2) ? wv : wo;
    wT = (wsel == 0) ? wqkvT : (wsel == 1) ? wqkvT + 1024*1024
       : (wsel == 2) ? wqkvT + 2*1024*1024 : woT;
  } else if (id < 8192) {
    int tt = id - 4096;
    K = 1024; N = 4096;
    n0 = (tt & 127) * 32; k0 = (tt >> 7) * 32;
    w = w1; wT = w1T;
  } else {
    int tt = id - 8192;
    K = 4096; N = 1024;
    n0 = (tt & 31) * 32; k0 = (tt >> 5) * 32;
    w = w2; wT = w2T;
  }
  int tx = threadIdx.x & 31, ty = threadIdx.x >> 5;
#pragma unroll
  for (int i = 0; i < 4; ++i)
    t[ty + 8*i][tx] = w[(size_t)(k0 + ty + 8*i) * N + n0 + tx];
  __syncthreads();
#pragma unroll
  for (int i = 0; i < 4; ++i)
    wT[(size_t)(n0 + ty + 8*i) * K + k0 + tx] = f2bf(t[tx][ty + 8*i]);
}

// ---------------------------------------------------------------------------
// LayerNorm (standalone, used for ln2).
// ---------------------------------------------------------------------------
__global__ __launch_bounds__(256) void ln_kernel(const float* __restrict__ x,
                                                 const float* __restrict__ w,
                                                 const float* __restrict__ b,
                                                 unsigned short* __restrict__ out) {
  int row  = blockIdx.x * 4 + (threadIdx.x >> 6);
  int lane = threadIdx.x & 63;
  const float4* xr = (const float4*)(x + (size_t)row * DIMSZ);
  float4 v[4];
  float s = 0.f, s2 = 0.f;
#pragma unroll
  for (int i = 0; i < 4; ++i) {
    v[i] = xr[lane + 64*i];
    s  += (v[i].x + v[i].y) + (v[i].z + v[i].w);
    s2 += (v[i].x*v[i].x + v[i].y*v[i].y) + (v[i].z*v[i].z + v[i].w*v[i].w);
  }
#pragma unroll
  for (int off = 32; off; off >>= 1) {
    s  += __shfl_xor(s,  off);
    s2 += __shfl_xor(s2, off);
  }
  float mean = s * (1.f/DIMSZ);
  float var  = s2 * (1.f/DIMSZ) - mean*mean;
  float rstd = rsqrtf(var + 1e-12f);
#pragma unroll
  for (int i = 0; i < 4; ++i) {
    float4 wv = ((const float4*)w)[lane + 64*i];
    float4 bv = ((const float4*)b)[lane + 64*i];
    ushort4 o;
    o.x = f2bf((v[i].x - mean) * rstd * wv.x + bv.x);
    o.y = f2bf((v[i].y - mean) * rstd * wv.y + bv.y);
    o.z = f2bf((v[i].z - mean) * rstd * wv.z + bv.z);
    o.w = f2bf((v[i].w - mean) * rstd * wv.w + bv.w);
    *(ushort4*)(out + (size_t)row * DIMSZ + (size_t)(lane + 64*i) * 4) = o;
  }
}

// ---------------------------------------------------------------------------
// V transpose: qkv[(b*S+s)*3072 + 2048 + h*64 + d] -> vt[(bh*64+d)*S + s]
// ---------------------------------------------------------------------------
__global__ __launch_bounds__(256) void vt_kernel(const unsigned short* __restrict__ qkv,
                                                 unsigned short* __restrict__ vt) {
  __shared__ unsigned short tile[64][65];
  int bh = blockIdx.y, b = bh >> 4, h = bh & 15;
  int s0 = blockIdx.x * 64;
  int tx = threadIdx.x & 63, ty = threadIdx.x >> 6;
#pragma unroll
  for (int i = 0; i < 16; ++i) {
    int s = ty + i*4;
    tile[s][tx] = qkv[((size_t)(b*SEQ) + s0 + s) * 3072 + 2048 + h*HD + tx];
  }
  __syncthreads();
#pragma unroll
  for (int i = 0; i < 16; ++i) {
    int d = ty + i*4;
    vt[((size_t)bh * HD + d) * SEQ + s0 + tx] = tile[tx][d];
  }
}

// ---------------------------------------------------------------------------
// GEMM (R4 structure — known good): C[M,N] = epi( A[M,K] @ Bt[N,K]^T ).
// Swapped MFMA operands (D = C^T tile -> vectorized epilogue). BK=64 staged
// as two 32-halves in one barrier-pair (32 MFMA between barriers).
// NT = 128 or 64. grid = (N/NT, M/128, Z); klen = K-range per z-slice.
// Z>1 (split-K): each slice writes its own DISJOINT output buffer at
// Cv + z*M*N (bf16) — no cross-XCD atomics (R8 lesson).
// EPI: 0 = bf16; 1 = bf16 gelu; 2 = f32 += res.
// ---------------------------------------------------------------------------
template<int EPI, int NT>
__global__ __launch_bounds__(256) void gemm_bt(const unsigned short* __restrict__ A,
                                               const unsigned short* __restrict__ Bt,
                                               void* __restrict__ Cv,
                                               const float* __restrict__ res,
                                               int M, int N, int K, int klen) {
  constexpr int JT = NT / 32;              // j-tiles per wave (4 or 2)
  __shared__ unsigned short As[2][128][32];
  __shared__ unsigned short Bs[2][NT][32];
  int tid  = threadIdx.x;
  int wv   = tid >> 6, lane = tid & 63, quad = lane >> 4, ml = lane & 15;
  int wrow = (wv >> 1) * 64, wcol = (wv & 1) * (NT/2);
  const unsigned short* Ab = A  + (size_t)blockIdx.y * 128 * K;
  const unsigned short* Bb = Bt + (size_t)blockIdx.x * NT  * K;
  int kbeg = blockIdx.z * klen;
  size_t zoff = (size_t)blockIdx.z * M * N;   // disjoint per-slice output

  f4_t acc[4][JT];
#pragma unroll
  for (int i = 0; i < 4; ++i)
#pragma unroll
    for (int j = 0; j < JT; ++j) acc[i][j] = (f4_t){0.f, 0.f, 0.f, 0.f};

  int r0 = tid >> 2, c0 = (tid & 3) * 8;   // 64 rows x 4 chunks of 8 bf16

  for (int k0 = kbeg; k0 < kbeg + klen; k0 += 64) {
#pragma unroll
    for (int h = 0; h < 2; ++h) {
      const unsigned short* ap = Ab + (size_t)r0 * K + k0 + h*32 + c0;
      async16(ap,          &As[h][r0][c0]);
      async16(ap + 64*K,   &As[h][r0 + 64][c0]);
      const unsigned short* bp = Bb + (size_t)r0 * K + k0 + h*32 + c0;
      async16(bp,          &Bs[h][r0][c0]);
      if constexpr (NT == 128)
        async16(bp + 64*K, &Bs[h][r0 + 64][c0]);
    }
    __syncthreads();

#pragma unroll
    for (int h = 0; h < 2; ++h) {
      bf8_t af[4], bfr[JT];
#pragma unroll
      for (int i = 0; i < 4; ++i)
        af[i] = *(const bf8_t*)(&As[h][wrow + i*16 + ml][quad * 8]);
#pragma unroll
      for (int j = 0; j < JT; ++j)
        bfr[j] = *(const bf8_t*)(&Bs[h][wcol + j*16 + ml][quad * 8]);
#pragma unroll
      for (int i = 0; i < 4; ++i)
#pragma unroll
        for (int j = 0; j < JT; ++j)
          acc[i][j] = mfma_bf16(bfr[j], af[i], acc[i][j]);   // swapped: D=C^T
    }
    __syncthreads();
  }

  // epilogue: lane holds C[m = wrow+i*16+ml][n = wcol+j*16+quad*4 .. +3]
#pragma unroll
  for (int i = 0; i < 4; ++i) {
    int m = blockIdx.y * 128 + wrow + i*16 + ml;
#pragma unroll
    for (int j = 0; j < JT; ++j) {
      int n = blockIdx.x * NT + wcol + j*16 + quad*4;
      size_t off = (size_t)m * N + n;
      if constexpr (EPI == 2) {
        float4 rv = *(const float4*)(res + off);
        float4 ov;
        ov.x = rv.x + acc[i][j][0];
        ov.y = rv.y + acc[i][j][1];
        ov.z = rv.z + acc[i][j][2];
        ov.w = rv.w + acc[i][j][3];
        *(float4*)((float*)Cv + off) = ov;
      } else {
        float v0 = acc[i][j][0], v1 = acc[i][j][1], v2 = acc[i][j][2], v3 = acc[i][j][3];
        if constexpr (EPI == 1) {
          v0 = gelu_fast(v0); v1 = gelu_fast(v1);
          v2 = gelu_fast(v2); v3 = gelu_fast(v3);
        }
        ushort4 o;
        o.x = f2bf(v0); o.y = f2bf(v1); o.z = f2bf(v2); o.w = f2bf(v3);
        *(ushort4*)((unsigned short*)Cv + zoff + off) = o;
      }
    }
  }
}

// ---------------------------------------------------------------------------
// W2 combine: out = x2 + p0 + p1 (bf16 partials -> fp32 out).
// grid = ROWS*DIMSZ/4/256 = 4096 blocks.
// ---------------------------------------------------------------------------
__global__ __launch_bounds__(256) void w2_combine(const unsigned short* __restrict__ p0,
                                                  const unsigned short* __restrict__ p1,
                                                  const float* __restrict__ x2,
                                                  float* __restrict__ out) {
  size_t t = ((size_t)blockIdx.x * 256 + threadIdx.x) * 4;
  ushort4 a = *(const ushort4*)(p0 + t);
  ushort4 c = *(const ushort4*)(p1 + t);
  float4 r  = *(const float4*)(x2 + t);
  float4 o;
  o.x = r.x + bf2f(a.x) + bf2f(c.x);
  o.y = r.y + bf2f(a.y) + bf2f(c.y);
  o.z = r.z + bf2f(a.z) + bf2f(c.z);
  o.w = r.w + bf2f(a.w) + bf2f(c.w);
  *(float4*)(out + t) = o;
}

// ---------------------------------------------------------------------------
// Flash attention partial (R6 structure — known good): 128 q-rows/block,
// 2 Q-frags per wave, split-K (KSPLIT=2). Fixed-base exp2 softmax.
// grid = (SEQ/128, KSPLIT, B*H), block 256.
// ---------------------------------------------------------------------------
__global__ __launch_bounds__(256) void attn_part(const unsigned short* __restrict__ qkv,
                                                 const unsigned short* __restrict__ vt,
                                                 const float* __restrict__ mask,
                                                 unsigned short* __restrict__ pbuf,
                                                 float* __restrict__ lbuf) {
  __shared__ unsigned short Ks[2][64][32];      // [d-half][key][d32]   8 KB
  __shared__ unsigned short Vs[2][64][32];      // [key-half][d][k32]   8 KB
  __shared__ unsigned short Ps[4][2][16][72];   // [wave][qfrag][q][key] 18 KB

  int kz = blockIdx.y;
  int bh = blockIdx.z, b = bh >> 4, h = bh & 15;
  int tid = threadIdx.x;
  int wv = tid >> 6, lane = tid & 63;
  int quad = lane >> 4, ml = lane & 15;
  int q0 = blockIdx.x * 128;
  int qA = q0 + wv * 32 + ml;               // frag 0 q row
  int qB = qA + 16;                         // frag 1 q row
  int kbeg = kz * KRANGE;

  const unsigned short* qrowA = qkv + ((size_t)(b*SEQ) + qA) * 3072 + h*HD;
  const unsigned short* qrowB = qkv + ((size_t)(b*SEQ) + qB) * 3072 + h*HD;
  bf8_t qf[2][2];
  qf[0][0] = *(const bf8_t*)(qrowA + quad*8);
  qf[0][1] = *(const bf8_t*)(qrowA + 32 + quad*8);
  qf[1][0] = *(const bf8_t*)(qrowB + quad*8);
  qf[1][1] = *(const bf8_t*)(qrowB + 32 + quad*8);

  const unsigned short* kbase = qkv + ((size_t)(b*SEQ) + kbeg) * 3072 + DIMSZ + h*HD;
  const unsigned short* vbase = vt + (size_t)bh * HD * SEQ + kbeg;
  const float* mrowA = mask + (size_t)qA * SEQ + kbeg;
  const float* mrowB = mask + (size_t)qB * SEQ + kbeg;

  int srow = tid >> 2;            // 0..63
  int scol = (tid & 3) * 8;       // 0,8,16,24 (ushorts)

  f4_t O[2][4];
#pragma unroll
  for (int g = 0; g < 2; ++g)
#pragma unroll
    for (int dt = 0; dt < 4; ++dt) O[g][dt] = (f4_t){0.f, 0.f, 0.f, 0.f};
  float lR[2] = {0.f, 0.f};

  const float C1 = 0.18033688011112042f;   // 0.125 * log2(e)
  const float C2 = 1.4426950408889634f;    // log2(e)

  for (int t0 = 0; t0 < KRANGE; t0 += 64) {
    float4 mvA[4], mvB[4];
#pragma unroll
    for (int mt = 0; mt < 4; ++mt) {
      mvA[mt] = *(const float4*)(mrowA + t0 + mt*16 + quad*4);
      mvB[mt] = *(const float4*)(mrowB + t0 + mt*16 + quad*4);
    }

    __syncthreads();   // previous chunk's K/V reads done before overwrite
#pragma unroll
    for (int dh = 0; dh < 2; ++dh)
      async16(kbase + (size_t)(t0 + srow) * 3072 + dh*32 + scol,
              &Ks[dh][0][0] + (size_t)tid * 8);
#pragma unroll
    for (int kc = 0; kc < 2; ++kc)
      async16(vbase + (size_t)srow * SEQ + t0 + kc*32 + scol,
              &Vs[kc][0][0] + (size_t)tid * 8);
    __syncthreads();   // staging visible

    // --- S^T = K·Q^T over 64 keys, both q-frags share the K reads ---
#pragma unroll
    for (int mt = 0; mt < 4; ++mt) {
      bf8_t kf0 = *(const bf8_t*)(&Ks[0][mt*16 + ml][quad*8]);
      bf8_t kf1 = *(const bf8_t*)(&Ks[1][mt*16 + ml][quad*8]);
#pragma unroll
      for (int g = 0; g < 2; ++g) {
        f4_t s = (f4_t){0.f, 0.f, 0.f, 0.f};
        s = mfma_bf16(kf0, qf[g][0], s);
        s = mfma_bf16(kf1, qf[g][1], s);
        const float4& mv = g ? mvB[mt] : mvA[mt];
        float p0 = fast_exp2(fmaf(s[0], C1, mv.x * C2));
        float p1 = fast_exp2(fmaf(s[1], C1, mv.y * C2));
        float p2 = fast_exp2(fmaf(s[2], C1, mv.z * C2));
        float p3 = fast_exp2(fmaf(s[3], C1, mv.w * C2));
        lR[g] += (p0 + p1) + (p2 + p3);
        uint2 pk;
        pk.x = pk_trunc_bf16(p0, p1);
        pk.y = pk_trunc_bf16(p2, p3);
        *(uint2*)(&Ps[wv][g][ml][mt*16 + quad*4]) = pk;
      }
    }

    // --- O^T += V^T·P^T, both q-frags share the V reads ---
#pragma unroll
    for (int kc = 0; kc < 2; ++kc) {
      bf8_t pfA = *(const bf8_t*)(&Ps[wv][0][ml][kc*32 + quad*8]);
      bf8_t pfB = *(const bf8_t*)(&Ps[wv][1][ml][kc*32 + quad*8]);
#pragma unroll
      for (int dt = 0; dt < 4; ++dt) {
        bf8_t vf = *(const bf8_t*)(&Vs[kc][dt*16 + ml][quad*8]);
        O[0][dt] = mfma_bf16(vf, pfA, O[0][dt]);
        O[1][dt] = mfma_bf16(vf, pfB, O[1][dt]);
      }
    }
  }

  // reduce l over quads; write partials (no divide)
#pragma unroll
  for (int g = 0; g < 2; ++g) {
    lR[g] += __shfl_xor(lR[g], 16);
    lR[g] += __shfl_xor(lR[g], 32);
    int q = g ? qB : qA;
    size_t pb = ((size_t)(bh * KSPLIT + kz) * SEQ + q) * HD;
#pragma unroll
    for (int dt = 0; dt < 4; ++dt) {
      ushort4 o;
      o.x = f2bf(O[g][dt][0]);
      o.y = f2bf(O[g][dt][1]);
      o.z = f2bf(O[g][dt][2]);
      o.w = f2bf(O[g][dt][3]);
      *(ushort4*)(pbuf + pb + dt*16 + quad*4) = o;
    }
    if (quad == 0)
      lbuf[(size_t)(bh * KSPLIT + kz) * SEQ + q] = lR[g];
  }
}

// ---------------------------------------------------------------------------
// Attention combine: O = (O0 + O1) / (l0 + l1), bf16 out [b,s,h*64+d].
// ---------------------------------------------------------------------------
__global__ __launch_bounds__(256) void attn_combine(const unsigned short* __restrict__ pbuf,
                                                    const float* __restrict__ lbuf,
                                                    unsigned short* __restrict__ attno) {
  int t = blockIdx.x * 256 + threadIdx.x;   // [0, BH*SEQ*16)
  int dchunk = t & 15;
  int q = (t >> 4) & (SEQ - 1);
  int bh = t >> 15;                         // SEQ*16 = 32768 = 2^15
  int b = bh >> 4, h = bh & 15;
  size_t o0 = ((size_t)(bh * KSPLIT + 0) * SEQ + q) * HD + dchunk * 4;
  size_t o1 = ((size_t)(bh * KSPLIT + 1) * SEQ + q) * HD + dchunk * 4;
  ushort4 a = *(const ushort4*)(pbuf + o0);
  ushort4 c = *(const ushort4*)(pbuf + o1);
  float l = lbuf[(size_t)(bh * KSPLIT + 0) * SEQ + q]
          + lbuf[(size_t)(bh * KSPLIT + 1) * SEQ + q];
  float inv = 1.f / l;
  ushort4 o;
  o.x = f2bf((bf2f(a.x) + bf2f(c.x)) * inv);
  o.y = f2bf((bf2f(a.y) + bf2f(c.y)) * inv);
  o.z = f2bf((bf2f(a.z) + bf2f(c.z)) * inv);
  o.w = f2bf((bf2f(a.w) + bf2f(c.w)) * inv);
  *(ushort4*)(attno + ((size_t)(b*SEQ) + q) * DIMSZ + h*HD + dchunk*4) = o;
}

// ---------------------------------------------------------------------------
extern "C" void kernel_launch(void* const* d_in, const int* in_sizes, int n_in,
                              void* d_out, int out_size, void* d_ws, size_t ws_size,
                              hipStream_t stream) {
  const float* x    = (const float*)d_in[0];
  const float* mask = (const float*)d_in[1];
  const float* wq   = (const float*)d_in[2];
  const float* wk   = (const float*)d_in[3];
  const float* wvp  = (const float*)d_in[4];
  const float* wo   = (const float*)d_in[5];
  const float* w1   = (const float*)d_in[6];
  const float* w2   = (const float*)d_in[7];
  const float* ln1w = (const float*)d_in[8];
  const float* ln1b = (const float*)d_in[9];
  const float* ln2w = (const float*)d_in[10];
  const float* ln2b = (const float*)d_in[11];
  float* out = (float*)d_out;

  char* ws = (char*)d_ws;
  unsigned short* wqkvT  = (unsigned short*)(ws + 0);           //  6 MiB [3072][1024]
  unsigned short* woT    = (unsigned short*)(ws + 6291456);     //  2 MiB [1024][1024]
  unsigned short* w1T    = (unsigned short*)(ws + 8388608);     //  8 MiB [4096][1024]
  unsigned short* w2T    = (unsigned short*)(ws + 16777216);    //  8 MiB [1024][4096]
  unsigned short* attno  = (unsigned short*)(ws + 25165824);    //  8 MiB [4096][1024]
  float*          x2     = (float*)         (ws + 33554432);    // 16 MiB [4096][1024]
  unsigned short* hbuf   = (unsigned short*)(ws + 50331648);    //  8 MiB h1 then h2
  unsigned short* qkvb   = (unsigned short*)(ws + 58720256);    // 24 MiB [4096][3072]
  unsigned short* vtb    = (unsigned short*)(ws + 83886080);    //  8 MiB [32][64][2048]
  unsigned short* gbuf   = (unsigned short*)(ws + 58720256);    // 32 MiB, reuses qkv+vt
  // attn split-K partials: pbuf in x2's region (consumed before WO writes x2),
  // lbuf at hbuf start (h1 consumed by QKV gemm; ln2 rewrites hbuf later).
  unsigned short* pbuf   = (unsigned short*)(ws + 33554432);
  float*          lbuf   = (float*)         (ws + 50331648);
  // W2 split-K partials: 2 x 8 MiB bf16 at ws[0..16.7M) — wqkvT/woT/w1T are
  // all dead by the time the W2 gemm runs (launch order serializes on stream).
  unsigned short* w2p    = (unsigned short*)(ws + 0);

  // 1. prep: ln1 + all weight transposes (one launch)
  prep_kernel<<<13312, 256, 0, stream>>>(x, ln1w, ln1b, hbuf,
      wq, wk, wvp, wo, w1, w2,
      wqkvT, woT, w1T, w2T);
  // 2. QKV projection
  gemm_bt<0,128><<<dim3(3072/128, 4096/128, 1), 256, 0, stream>>>(hbuf, wqkvT, qkvb, nullptr, ROWS, 3072, 1024, 1024);
  // 3. V -> dim-major
  vt_kernel<<<dim3(SEQ/64, BATCH*NHEAD), 256, 0, stream>>>(qkvb, vtb);
  // 4. attention (split-K partials) + combine
  attn_part<<<dim3(SEQ/128, KSPLIT, BATCH*NHEAD), 256, 0, stream>>>(qkvb, vtb, mask, pbuf, lbuf);
  attn_combine<<<(BATCH*NHEAD*SEQ*(HD/4))/256, 256, 0, stream>>>(pbuf, lbuf, attno);
  // 5. x2 = x + attn @ wo
  gemm_bt<2,64><<<dim3(1024/64, 4096/128, 1), 256, 0, stream>>>(attno, woT, x2, x, ROWS, 1024, 1024, 1024);
  // 6. ln2 -> h2
  ln_kernel<<<ROWS/4, 256, 0, stream>>>(x2, ln2w, ln2b, hbuf);
  // 7. g = gelu(h2 @ w1)
  gemm_bt<1,128><<<dim3(4096/128, 4096/128, 1), 256, 0, stream>>>(hbuf, w1T, gbuf, nullptr, ROWS, FFNSZ, 1024, 1024);
  // 8. W2 split-K=2 -> disjoint bf16 partial buffers (XCD-safe)
  gemm_bt<0,64><<<dim3(1024/64, 4096/128, 2), 256, 0, stream>>>(gbuf, w2T, w2p, nullptr, ROWS, 1024, 4096, 2048);
  // 9. out = x2 + p0 + p1
  w2_combine<<<(ROWS*DIMSZ/4)/256, 256, 0, stream>>>(w2p, w2p + (size_t)ROWS*DIMSZ, x2, out);

  (void)in_sizes; (void)n_in; (void)out_size; (void)ws_size;
}